// Round 2
// baseline (630.229 us; speedup 1.0000x reference)
//
#include <hip/hip_runtime.h>
#include <hip/hip_bf16.h>
#include <math.h>

// Problem constants (B=4, S=2048, D_IN=D_OUT=2048, H=16, HD=128)
#define H_   16
#define S_   2048
#define D_   2048
#define HD_  128
#define B_   4
#define M_   8192   // B*S

typedef __attribute__((ext_vector_type(8))) short short8;   // 8 bf16
typedef __attribute__((ext_vector_type(4))) short short4v;
typedef __attribute__((ext_vector_type(4))) float f32x4;

__device__ __forceinline__ short f2bf(float f) {
  unsigned u = __float_as_uint(f);
  u += 0x7fff + ((u >> 16) & 1);
  return (short)(u >> 16);
}

__device__ __forceinline__ unsigned pk2(float a, float b) {
  __hip_bfloat162 h = __float22bfloat162_rn(float2{a, b});
  union { __hip_bfloat162 h2; unsigned u; } c;
  c.h2 = h;
  return c.u;
}

__device__ __forceinline__ void async16(const void* g, void* l) {
  // 16B/lane, LDS dest = wave-uniform base + lane*16 (m97/m104 semantics)
  __builtin_amdgcn_global_load_lds(
      (const __attribute__((address_space(1))) void*)g,
      (__attribute__((address_space(3))) void*)l, 16, 0, 0);
}

// ---------------------------------------------------------------- cast x -> bf16
__global__ void k_cvtx(const float* __restrict__ x, short* __restrict__ o, int n4) {
  const int i = blockIdx.x * 256 + threadIdx.x;
  if (i >= n4) return;
  const float4 f = ((const float4*)x)[i];
  short4v s;
  s.x = f2bf(f.x); s.y = f2bf(f.y); s.z = f2bf(f.z); s.w = f2bf(f.w);
  ((short4v*)o)[i] = s;
}

// ------------------------------------------- W[K][N] fp32 -> Wt[N][K] bf16 (tiled)
__global__ void k_wtrans(const float* __restrict__ W, short* __restrict__ Wt) {
  __shared__ float t[32][33];
  const int n0 = blockIdx.x << 5, k0 = blockIdx.y << 5;
  const int tc = threadIdx.x & 31, tr = threadIdx.x >> 5;
#pragma unroll
  for (int i = 0; i < 32; i += 8)
    t[tr + i][tc] = W[(size_t)(k0 + tr + i) * D_ + n0 + tc];
  __syncthreads();
#pragma unroll
  for (int i = 0; i < 32; i += 8)
    Wt[(size_t)(n0 + tr + i) * D_ + k0 + tc] = f2bf(t[tc][tr + i]);
}

// =============================================================================
// 256x256 8-phase bf16 GEMM (m201-template port, v2).  C = A[M,K]*Bt[N,K]^T.
// 8 waves (2M x 4N), per-wave 128x64 out, BK=64, LDS 128 KiB (1 block/CU).
//
// v2 re-phasing: phase = (A-half mh, k-slice ks) — matches the m201 template
// shape exactly: every phase = {4 or 8 ds_read_b128} + {exactly 2
// global_load_lds (1 half-tile)} + bar + {16 INDEPENDENT MFMA} + bar.
//   P1 (mh0,ks0): read af=A0[ks0](4) + bf0=B[ks0](4);  stage A0(T+1)
//   P2 (mh0,ks1): read af=A0[ks1](4) + bf1=B[ks1](4);  stage A1(T+1)
//   P3 (mh1,ks0): read af=A1[ks0](4), reuse bf0;       stage B0(T+2)
//   P4 (mh1,ks1): read af=A1[ks1](4), reuse bf1;       stage B1(T+2); vmcnt(4)
// Ledger (stage @issue -> buffer last-read -> slack):
//   A0(T+1)@[T,P1] -> As[b^1][0] read [T-1,P2]  (>=1 barrier)
//   A1(T+1)@[T,P2] -> As[b^1][1] read [T-1,P4]  (>=1 barrier)
//   B0(T+2)@[T,P3] -> Bs[b][0]   read [T,P2]    (1 barrier)
//   B1(T+2)@[T,P4] -> Bs[b][1]   read [T,P2]    (2 barriers)
// vmcnt(4) at [T,P4]: outstanding = {B0,B1}(T+1)[2 STG] + P1..P4 stages[4 STG]
// = 12 loads; retire 8 = tile T+1 complete; leave {B0,B1}(T+2) = 4.  Tail:
// vmcnt(0) at [NT-2,P4].  Prologue: 6 STG {tile0, B0(1),B1(1)}, vmcnt(4).
//
// LDS swizzle: byte ^= (row&7)<<4 applied to the pre-swizzled GLOBAL source
// (global_load_lds writes linearly) and to the ds_read_b128 address ->
// 0 bank conflicts (verified R1: SQ_LDS_BANK_CONFLICT 2.5e7 -> 0).
// =============================================================================

#define GBAR() asm volatile("s_barrier" ::: "memory")

#define STG_A(b, mh, t)                                           \
  do {                                                            \
    const size_t o_ = (size_t)(t) * 64 + (size_t)(mh) * 64 * K;   \
    async16(Ag0 + o_, &As[b][mh][ldst]);                          \
    async16(Ag1 + o_, &As[b][mh][4096 + ldst]);                   \
  } while (0)

#define STG_B(b, nh, t)                                           \
  do {                                                            \
    const size_t o_ = (size_t)(t) * 64 + (size_t)(nh) * 32 * K;   \
    async16(Bg0 + o_, &Bs[b][nh][ldst]);                          \
    async16(Bg1 + o_, &Bs[b][nh][4096 + ldst]);                   \
  } while (0)

#define LDS_AF(b, mh, CC)                                                \
  do {                                                                   \
    const char* a_ = (const char*)&As[b][mh][0];                         \
    _Pragma("unroll") for (int mi_ = 0; mi_ < 4; ++mi_)                  \
      af[mi_] = *(const short8*)(a_ + rdA + mi_ * 2048 + (CC));          \
  } while (0)

#define LDS_BF(b, CC, BF)                                                \
  do {                                                                   \
    const char* b0_ = (const char*)&Bs[b][0][0];                         \
    const char* b1_ = (const char*)&Bs[b][1][0];                         \
    BF[0] = *(const short8*)(b0_ + rdB + (CC));                          \
    BF[1] = *(const short8*)(b0_ + rdB + 2048 + (CC));                   \
    BF[2] = *(const short8*)(b1_ + rdB + (CC));                          \
    BF[3] = *(const short8*)(b1_ + rdB + 2048 + (CC));                   \
  } while (0)

// 16 mutually independent MFMAs (k-accumulation chains across phases, not
// within a phase) — lets the matrix pipe pack back-to-back.
#define QUADX(mh, BF)                                                     \
  do {                                                                    \
    __builtin_amdgcn_s_setprio(1);                                        \
    _Pragma("unroll") for (int mi_ = 0; mi_ < 4; ++mi_)                   \
    _Pragma("unroll") for (int ni_ = 0; ni_ < 4; ++ni_)                   \
      acc[(mh) * 4 + mi_][ni_] = __builtin_amdgcn_mfma_f32_16x16x32_bf16( \
          af[mi_], BF[ni_], acc[(mh) * 4 + mi_][ni_], 0, 0, 0);           \
    __builtin_amdgcn_s_setprio(0);                                        \
  } while (0)

#define TILE(T, b)                                                  \
  do {                                                              \
    /* ---- P1: (mh0, ks0) ---- */                                  \
    LDS_AF(b, 0, cc0);                                              \
    LDS_BF(b, cc0, bf0);                                            \
    if ((T) + 1 < NT) STG_A((b) ^ 1, 0, (T) + 1);                   \
    GBAR();                                                         \
    QUADX(0, bf0);                                                  \
    GBAR();                                                         \
    /* ---- P2: (mh0, ks1) ---- */                                  \
    LDS_AF(b, 0, cc1);                                              \
    LDS_BF(b, cc1, bf1);                                            \
    if ((T) + 1 < NT) STG_A((b) ^ 1, 1, (T) + 1);                   \
    GBAR();                                                         \
    QUADX(0, bf1);                                                  \
    GBAR();                                                         \
    /* ---- P3: (mh1, ks0) ---- */                                  \
    LDS_AF(b, 1, cc0);                                              \
    if ((T) + 2 < NT) STG_B(b, 0, (T) + 2);                         \
    GBAR();                                                         \
    QUADX(1, bf0);                                                  \
    GBAR();                                                         \
    /* ---- P4: (mh1, ks1) ---- */                                  \
    LDS_AF(b, 1, cc1);                                              \
    if ((T) + 2 < NT) STG_B(b, 1, (T) + 2);                         \
    if ((T) + 2 < NT)                                               \
      asm volatile("s_waitcnt vmcnt(4)" ::: "memory");              \
    else if ((T) + 1 < NT)                                          \
      asm volatile("s_waitcnt vmcnt(0)" ::: "memory");              \
    GBAR();                                                         \
    QUADX(1, bf1);                                                  \
    GBAR();                                                         \
  } while (0)

// MODE 0: fused QKV epilogue (N=6144): proj = bn>>11 -> Q/K scatter [b,h,s,hd],
//         V^T pack [b,h,hd,s]. MODE 1: fp32 [m][n] + bias.
template <int MODE>
__global__ __launch_bounds__(512, 2)
void k_gemm256(const short* __restrict__ A, const short* __restrict__ Bt,
               void* __restrict__ C0, void* __restrict__ C1, void* __restrict__ C2,
               const float* __restrict__ bias, int M, int N, int K) {
  __shared__ __align__(16) short As[2][2][8192];   // [buf][half][128 rows x 64 k]
  __shared__ __align__(16) short Bs[2][2][8192];
  const int tid = threadIdx.x;
  const int lane = tid & 63;
  const int wave = tid >> 6;
  const int ln = lane & 15, lq = lane >> 4;
  const int wr = wave >> 2, wc = wave & 3;        // 2M x 4N wave grid
  const int bn = blockIdx.x << 8;
  const int bm = blockIdx.y << 8;
  const int NT = K >> 6;

  // --- staging sources: lane covers LDS bytes [wave*1024 + lane*16) (+8192 for
  // inst 1).  r0 = row-in-half for inst0 (inst1 = r0+64, same k0).  k0 is the
  // inverse-swizzled k so linear LDS dest ends up swizzle-correct.
  const int r0 = wave * 8 + (lane >> 3);
  const int k0 = ((lane & 7) ^ ((lane >> 3) & 7)) << 3;
  const short* Ag0 = A  + (size_t)(bm + r0) * K + k0;
  const short* Ag1 = A  + (size_t)(bm + 128 + r0) * K + k0;
  const short* Bg0 = Bt + (size_t)(bn + ((r0 >> 5) << 6) + (r0 & 31)) * K + k0;
  const short* Bg1 = Bt + (size_t)(bn + (((r0 >> 5) + 2) << 6) + (r0 & 31)) * K + k0;
  const int ldst = wave * 512;                    // wave's 1 KiB chunk (shorts)

  // --- ds_read byte offsets (swizzled): row-in-half * 128 + ((ks*64+lq*16)^swz)
  const int swz = (ln & 7) << 4;
  const int rdA = (wr * 64 + ln) * 128;           // + mi*2048
  const int rdB = (wc * 32 + ln) * 128;           // + ni(0/1)*2048; halves for ni 2,3
  const int cc0 = (lq * 16) ^ swz;                // ks = 0
  const int cc1 = (64 + lq * 16) ^ swz;           // ks = 1

  f32x4 acc[8][4];
#pragma unroll
  for (int i = 0; i < 8; i++)
#pragma unroll
    for (int j = 0; j < 4; j++) acc[i][j] = (f32x4)0.0f;

  // --- prologue: tile0 {A0,A1,B0,B1} + tile1 {B0,B1}; vmcnt(4) retires tile0
  STG_A(0, 0, 0);
  STG_A(0, 1, 0);
  STG_B(0, 0, 0);
  STG_B(0, 1, 0);
  STG_B(1, 0, 1);
  STG_B(1, 1, 1);
  asm volatile("s_waitcnt vmcnt(4)" ::: "memory");
  GBAR();

  short8 af[4];
  short8 bf0[4], bf1[4];

#pragma unroll 1
  for (int T = 0; T < NT; T += 2) {
    TILE(T, 0);
    TILE(T + 1, 1);
  }

  // --- epilogue (C/D layout: col=lane&15, row=(lane>>4)*4+reg — m89/m91)
  if (MODE == 0) {
    const int proj = bn >> 11;        // 0=Q, 1=K, 2=V (block-uniform, 256|2048)
    const int cb = bn & 2047;
    if (proj < 2) {
      short* C = (short*)(proj == 0 ? C0 : C1);
#pragma unroll
      for (int mi = 0; mi < 8; mi++)
#pragma unroll
        for (int ni = 0; ni < 4; ni++) {
          const int col = cb + wc * 64 + ni * 16 + ln;
          const int h = col >> 7, d = col & 127;
#pragma unroll
          for (int r = 0; r < 4; r++) {
            const int row = bm + wr * 128 + mi * 16 + lq * 4 + r;
            const int bb = row >> 11, s = row & 2047;
            C[((size_t)((bb * H_ + h) * S_ + s)) * HD_ + d] = f2bf(acc[mi][ni][r]);
          }
        }
    } else {  // V^T [b,h,d,s], r-regs = 4 consecutive s -> b64 store
      short* C = (short*)C2;
#pragma unroll
      for (int mi = 0; mi < 8; mi++)
#pragma unroll
        for (int ni = 0; ni < 4; ni++) {
          const int col = cb + wc * 64 + ni * 16 + ln;
          const int h = col >> 7, d = col & 127;
          const int row0 = bm + wr * 128 + mi * 16 + lq * 4;
          const int bb = row0 >> 11, s = row0 & 2047;
          short4v pk;
#pragma unroll
          for (int r = 0; r < 4; r++) pk[r] = f2bf(acc[mi][ni][r]);
          *(short4v*)(C + ((size_t)((bb * H_ + h) * HD_ + d)) * S_ + s) = pk;
        }
    }
  } else {
    float* C = (float*)C0;
#pragma unroll
    for (int mi = 0; mi < 8; mi++)
#pragma unroll
      for (int ni = 0; ni < 4; ni++) {
        const int col = bn + wc * 64 + ni * 16 + ln;
        const float bv = bias[col];
#pragma unroll
        for (int r = 0; r < 4; r++) {
          const int row = bm + wr * 128 + mi * 16 + lq * 4 + r;
          C[(size_t)row * N + col] = acc[mi][ni][r] + bv;
        }
      }
  }
}

// ---------------------------------------------------------------- flash attention
// (unchanged — 191 us; occupancy/latency redesign is a later round)
__global__ __launch_bounds__(256)
void k_flash(const short* __restrict__ Q, const short* __restrict__ K,
             const short* __restrict__ Vt, short* __restrict__ ctx) {
  __shared__ __align__(16) short Ks[2][64 * 128];
  __shared__ __align__(16) short Vs[2][128 * 64];
  __shared__ __align__(16) short Ps[4 * 32 * 64];

  const int tid = threadIdx.x, lane = tid & 63, w = tid >> 6;
  const int ln = lane & 15, lq = lane >> 4;
  const int bh = blockIdx.x & 63;
  const int pr = blockIdx.x >> 6;
  const int b = bh >> 4, h = bh & 15;
  const short* Qp = Q  + (size_t)bh * S_ * HD_;
  const short* Kp = K  + (size_t)bh * S_ * HD_;
  const short* Vp = Vt + (size_t)bh * HD_ * S_;

  const float sc = 0.08838834764831845f * 1.4426950408889634f;
  const int lx = ln & 7;

  int koff[4], voff[4];
#pragma unroll
  for (int it = 0; it < 4; it++) {
    const int kr = w * 16 + it * 4 + (lane >> 4);
    koff[it] = kr * HD_ + (((lane & 15) ^ (kr & 7)) * 8);
    const int vr = w * 32 + it * 8 + (lane >> 3);
    voff[it] = vr * S_ + (((lane & 7) ^ (vr & 7)) * 8);
  }

#pragma unroll 1
  for (int pass = 0; pass < 2; pass++) {
    const int qb = pass ? (15 - pr) : pr;
    const int q0 = qb << 7;
    const int qw = q0 + w * 32;
    const int nkt = qb * 2 + 2;

    short8 qf[2][4];
#pragma unroll
    for (int nt = 0; nt < 2; nt++)
#pragma unroll
      for (int c = 0; c < 4; c++)
        qf[nt][c] = *(const short8*)(Qp + (size_t)(qw + nt * 16 + ln) * HD_ + c * 32 + lq * 8);

    f32x4 acc[8][2];
#pragma unroll
    for (int t = 0; t < 8; t++) { acc[t][0] = (f32x4)0.0f; acc[t][1] = (f32x4)0.0f; }
    float l_i[2] = {0.0f, 0.0f};

    __syncthreads();
#pragma unroll
    for (int it = 0; it < 4; it++) {
      async16(Kp + koff[it], &Ks[0][(w * 16 + it * 4) * 128]);
      async16(Vp + voff[it], &Vs[0][(w * 32 + it * 8) * 64]);
    }

#pragma unroll 1
    for (int kt = 0; kt < nkt; kt++) {
      const int k0 = kt << 6;
      const int cur = kt & 1;
      __syncthreads();
      if (kt + 1 < nkt) {
        const int nk0 = (kt + 1) << 6;
        const int nb = cur ^ 1;
#pragma unroll
        for (int it = 0; it < 4; it++) {
          async16(Kp + (size_t)nk0 * HD_ + koff[it], &Ks[nb][(w * 16 + it * 4) * 128]);
          async16(Vp + nk0 + voff[it],               &Vs[nb][(w * 32 + it * 8) * 64]);
        }
      }

      if (k0 <= qw + 31) {
        const short* KsC = Ks[cur];
        const short* VsC = Vs[cur];
        short* Pw = Ps + w * 32 * 64;
        const bool dg = (k0 + 63 > qw);

#pragma unroll
        for (int mt = 0; mt < 4; mt++) {
          f32x4 s0 = (f32x4)0.0f, s1 = (f32x4)0.0f;
#pragma unroll
          for (int c = 0; c < 4; c++) {
            short8 kf = *(const short8*)(KsC + (mt * 16 + ln) * 128 + (((4 * c + lq) ^ lx) * 8));
            s0 = __builtin_amdgcn_mfma_f32_16x16x32_bf16(kf, qf[0][c], s0, 0, 0, 0);
            s1 = __builtin_amdgcn_mfma_f32_16x16x32_bf16(kf, qf[1][c], s1, 0, 0, 0);
          }
          if (dg) {
#pragma unroll
            for (int r = 0; r < 4; r++) {
              const int kv = k0 + mt * 16 + lq * 4 + r;
              if (kv > qw + ln)      s0[r] = -INFINITY; else s0[r] *= sc;
              if (kv > qw + 16 + ln) s1[r] = -INFINITY; else s1[r] *= sc;
            }
          } else {
#pragma unroll
            for (int r = 0; r < 4; r++) { s0[r] *= sc; s1[r] *= sc; }
          }
#pragma unroll
          for (int r = 0; r < 4; r++) {
            s0[r] = exp2f(s0[r]); l_i[0] += s0[r];
            s1[r] = exp2f(s1[r]); l_i[1] += s1[r];
          }
          const int swc = (2 * mt + (lq >> 1)) ^ lx;
          const int po = swc * 8 + (lq & 1) * 4;
          *(uint2*)(Pw + ln * 64 + po)        = uint2{pk2(s0[0], s0[1]), pk2(s0[2], s0[3])};
          *(uint2*)(Pw + (16 + ln) * 64 + po) = uint2{pk2(s1[0], s1[1]), pk2(s1[2], s1[3])};
        }
        __asm__ volatile("s_waitcnt lgkmcnt(0)" ::: "memory");

#pragma unroll
        for (int c = 0; c < 2; c++) {
          const int swr = ((4 * c + lq) ^ lx) * 8;
          short8 pf0 = *(const short8*)(Pw + ln * 64 + swr);
          short8 pf1 = *(const short8*)(Pw + (16 + ln) * 64 + swr);
#pragma unroll
          for (int t = 0; t < 8; t++) {
            short8 vf = *(const short8*)(VsC + (t * 16 + ln) * 64 + swr);
            acc[t][0] = __builtin_amdgcn_mfma_f32_16x16x32_bf16(vf, pf0, acc[t][0], 0, 0, 0);
            acc[t][1] = __builtin_amdgcn_mfma_f32_16x16x32_bf16(vf, pf1, acc[t][1], 0, 0, 0);
          }
        }
      }
    }

#pragma unroll
    for (int o = 16; o < 64; o <<= 1) {
      l_i[0] += __shfl_xor(l_i[0], o, 64);
      l_i[1] += __shfl_xor(l_i[1], o, 64);
    }
    const float il[2] = {1.0f / l_i[0], 1.0f / l_i[1]};

#pragma unroll
    for (int t = 0; t < 8; t++)
#pragma unroll
      for (int nt = 0; nt < 2; nt++) {
        const int q = qw + nt * 16 + ln;
        const int d = t * 16 + lq * 4;
        uint2 o2 = {pk2(acc[t][nt][0] * il[nt], acc[t][nt][1] * il[nt]),
                    pk2(acc[t][nt][2] * il[nt], acc[t][nt][3] * il[nt])};
        *(uint2*)(ctx + ((size_t)(b * S_ + q)) * D_ + h * HD_ + d) = o2;
      }
  }
}

// ---------------------------------------------------------------- launch
extern "C" void kernel_launch(void* const* d_in, const int* in_sizes, int n_in,
                              void* d_out, int out_size, void* d_ws, size_t ws_size,
                              hipStream_t stream) {
  const float* x  = (const float*)d_in[0];
  const float* Wq = (const float*)d_in[1];
  const float* Wk = (const float*)d_in[2];
  const float* Wv = (const float*)d_in[3];
  const float* Wo = (const float*)d_in[4];
  const float* bo = (const float*)d_in[5];
  float* out = (float*)d_out;

  char* ws = (char*)d_ws;
  const size_t SZ_X = (size_t)M_ * D_ * sizeof(short);
  const size_t SZ_W = (size_t)D_ * D_ * sizeof(short);
  short* xb  = (short*)(ws);
  short* Wqt = (short*)(ws + SZ_X);                     // Wqt|Wkt|Wvt contiguous
  short* Wkt = (short*)(ws + SZ_X + SZ_W);              //  = fused B^T [6144][2048]
  short* Wvt = (short*)(ws + SZ_X + 2 * SZ_W);
  short* Wot = (short*)(ws + SZ_X + 3 * SZ_W);
  short* Qb  = (short*)(ws + SZ_X + 4 * SZ_W);
  short* Kb  = (short*)(ws + 2 * SZ_X + 4 * SZ_W);
  short* Vtb = (short*)(ws + 3 * SZ_X + 4 * SZ_W);      // V^T [b,h,d,s]
  short* ctx = (short*)(ws + 4 * SZ_X + 4 * SZ_W);      // total 192 MiB

  k_cvtx<<<M_ * D_ / 4 / 256, 256, 0, stream>>>(x, xb, M_ * D_ / 4);
  dim3 tg(D_ / 32, D_ / 32);
  k_wtrans<<<tg, 256, 0, stream>>>(Wq, Wqt);
  k_wtrans<<<tg, 256, 0, stream>>>(Wk, Wkt);
  k_wtrans<<<tg, 256, 0, stream>>>(Wv, Wvt);
  k_wtrans<<<tg, 256, 0, stream>>>(Wo, Wot);

  // fused QKV projection: N=6144, 768 blocks (24x32), 512 thr, 1 block/CU
  dim3 gq(3 * D_ / 256, M_ / 256);
  k_gemm256<0><<<gq, 512, 0, stream>>>(xb, Wqt, Qb, Kb, Vtb, nullptr, M_, 3 * D_, D_);

  k_flash<<<8 * 64, 256, 0, stream>>>(Qb, Kb, Vtb, ctx);

  // output projection: 256 blocks (8x32) = exactly 1 pass over 256 CUs
  dim3 go(D_ / 256, M_ / 256);
  k_gemm256<1><<<go, 512, 0, stream>>>(ctx, Wot, out, nullptr, nullptr, bo, M_, D_, D_);
}

// Round 3
// 553.381 us; speedup vs baseline: 1.1389x; 1.1389x over previous
//
#include <hip/hip_runtime.h>
#include <hip/hip_bf16.h>
#include <math.h>

// Problem constants (B=4, S=2048, D_IN=D_OUT=2048, H=16, HD=128)
#define H_   16
#define S_   2048
#define D_   2048
#define HD_  128
#define B_   4
#define M_   8192   // B*S

typedef __attribute__((ext_vector_type(8))) short short8;   // 8 bf16
typedef __attribute__((ext_vector_type(4))) short short4v;
typedef __attribute__((ext_vector_type(4))) float f32x4;

__device__ __forceinline__ short f2bf(float f) {
  unsigned u = __float_as_uint(f);
  u += 0x7fff + ((u >> 16) & 1);
  return (short)(u >> 16);
}

__device__ __forceinline__ unsigned pk2(float a, float b) {
  __hip_bfloat162 h = __float22bfloat162_rn(float2{a, b});
  union { __hip_bfloat162 h2; unsigned u; } c;
  c.h2 = h;
  return c.u;
}

__device__ __forceinline__ void async16(const void* g, void* l) {
  // 16B/lane, LDS dest = wave-uniform base + lane*16 (m97/m104 semantics)
  __builtin_amdgcn_global_load_lds(
      (const __attribute__((address_space(1))) void*)g,
      (__attribute__((address_space(3))) void*)l, 16, 0, 0);
}

// ---------------------------------------------------------------- cast x -> bf16
__global__ void k_cvtx(const float* __restrict__ x, short* __restrict__ o, int n4) {
  const int i = blockIdx.x * 256 + threadIdx.x;
  if (i >= n4) return;
  const float4 f = ((const float4*)x)[i];
  short4v s;
  s.x = f2bf(f.x); s.y = f2bf(f.y); s.z = f2bf(f.z); s.w = f2bf(f.w);
  ((short4v*)o)[i] = s;
}

// ------------------------------------------- W[K][N] fp32 -> Wt[N][K] bf16 (tiled)
__global__ void k_wtrans(const float* __restrict__ W, short* __restrict__ Wt) {
  __shared__ float t[32][33];
  const int n0 = blockIdx.x << 5, k0 = blockIdx.y << 5;
  const int tc = threadIdx.x & 31, tr = threadIdx.x >> 5;
#pragma unroll
  for (int i = 0; i < 32; i += 8)
    t[tr + i][tc] = W[(size_t)(k0 + tr + i) * D_ + n0 + tc];
  __syncthreads();
#pragma unroll
  for (int i = 0; i < 32; i += 8)
    Wt[(size_t)(n0 + tr + i) * D_ + k0 + tc] = f2bf(t[tc][tr + i]);
}

// =============================================================================
// 256x256 8-phase bf16 GEMM — R1 schedule (measured 222 us QKV, MfmaUtil 39.7,
// bank conflicts 0).  C[M,N] = A[M,K]*Bt[N,K]^T.  8 waves (2M x 4N), per-wave
// 128x64 out, BK=64, LDS 128 KiB (1 block/CU).  Quadrant phases (mh,nh) with
// per-phase {ds_read burst + 1 half-tile stage + bar + 16 MFMA + bar};
// vmcnt(6) once per K-tile (3 half-tiles in flight), vmcnt(0) drain at NT-2.
// LDS swizzle byte ^= (row&7)<<4 on pre-swizzled global source + ds_read addr.
// =============================================================================

#define GBAR() asm volatile("s_barrier" ::: "memory")
#define WLG0()                                          \
  do {                                                  \
    asm volatile("s_waitcnt lgkmcnt(0)" ::: "memory");  \
    __builtin_amdgcn_sched_barrier(0);                  \
  } while (0)

#define STG_A(b, mh, t)                                           \
  do {                                                            \
    const size_t o_ = (size_t)(t) * 64 + (size_t)(mh) * 64 * K;   \
    async16(Ag0 + o_, &As[b][mh][ldst]);                          \
    async16(Ag1 + o_, &As[b][mh][4096 + ldst]);                   \
  } while (0)

#define STG_B(b, nh, t)                                           \
  do {                                                            \
    const size_t o_ = (size_t)(t) * 64 + (size_t)(nh) * 32 * K;   \
    async16(Bg0 + o_, &Bs[b][nh][ldst]);                          \
    async16(Bg1 + o_, &Bs[b][nh][4096 + ldst]);                   \
  } while (0)

#define LDS_A(b, mh)                                                     \
  do {                                                                   \
    const char* a_ = (const char*)&As[b][mh][0];                         \
    _Pragma("unroll") for (int mi_ = 0; mi_ < 4; ++mi_) {                \
      af[mi_ * 2]     = *(const short8*)(a_ + rdA + mi_ * 2048 + cc0);   \
      af[mi_ * 2 + 1] = *(const short8*)(a_ + rdA + mi_ * 2048 + cc1);   \
    }                                                                    \
  } while (0)

#define LDS_B(b, nh, BF)                                                 \
  do {                                                                   \
    const char* b_ = (const char*)&Bs[b][nh][0];                         \
    _Pragma("unroll") for (int ni_ = 0; ni_ < 2; ++ni_) {                \
      BF[ni_ * 2]     = *(const short8*)(b_ + rdB + ni_ * 2048 + cc0);   \
      BF[ni_ * 2 + 1] = *(const short8*)(b_ + rdB + ni_ * 2048 + cc1);   \
    }                                                                    \
  } while (0)

#define QUAD(mh, nh, BF)                                                   \
  do {                                                                     \
    __builtin_amdgcn_s_setprio(1);                                         \
    _Pragma("unroll") for (int mi_ = 0; mi_ < 4; ++mi_)                    \
    _Pragma("unroll") for (int ni_ = 0; ni_ < 2; ++ni_) {                  \
      acc[(mh) * 4 + mi_][(nh) * 2 + ni_] =                                \
          __builtin_amdgcn_mfma_f32_16x16x32_bf16(                         \
              af[mi_ * 2], BF[ni_ * 2],                                    \
              acc[(mh) * 4 + mi_][(nh) * 2 + ni_], 0, 0, 0);               \
      acc[(mh) * 4 + mi_][(nh) * 2 + ni_] =                                \
          __builtin_amdgcn_mfma_f32_16x16x32_bf16(                         \
              af[mi_ * 2 + 1], BF[ni_ * 2 + 1],                            \
              acc[(mh) * 4 + mi_][(nh) * 2 + ni_], 0, 0, 0);               \
    }                                                                      \
    __builtin_amdgcn_s_setprio(0);                                         \
  } while (0)

#define TILE(T, b)                                                  \
  do {                                                              \
    /* ---- phase q=1: quadrant (0,0) ---- */                       \
    LDS_A(b, 0);                                                    \
    LDS_B(b, 0, bf0);                                               \
    if ((T) + 1 < NT) STG_A((b) ^ 1, 1, (T) + 1);                   \
    asm volatile("s_waitcnt lgkmcnt(8)" ::: "memory");              \
    GBAR();                                                         \
    WLG0();                                                         \
    QUAD(0, 0, bf0);                                                \
    GBAR();                                                         \
    /* ---- phase q=2: quadrant (0,1) ---- */                       \
    LDS_B(b, 1, bf1);                                               \
    if ((T) + 2 < NT) STG_A(b, 0, (T) + 2);                         \
    GBAR();                                                         \
    WLG0();                                                         \
    QUAD(0, 1, bf1);                                                \
    GBAR();                                                         \
    /* ---- phase q=3: quadrant (1,0) ---- */                       \
    LDS_A(b, 1);                                                    \
    if ((T) + 2 < NT) STG_B(b, 0, (T) + 2);                         \
    GBAR();                                                         \
    WLG0();                                                         \
    QUAD(1, 0, bf0);                                                \
    GBAR();                                                         \
    /* ---- phase q=4: quadrant (1,1) ---- */                       \
    if ((T) + 2 < NT) STG_B(b, 1, (T) + 2);                         \
    if ((T) + 2 < NT)                                               \
      asm volatile("s_waitcnt vmcnt(6)" ::: "memory");              \
    else if ((T) + 1 < NT)                                          \
      asm volatile("s_waitcnt vmcnt(0)" ::: "memory");              \
    GBAR();                                                         \
    QUAD(1, 1, bf1);                                                \
    GBAR();                                                         \
  } while (0)

// MODE 0: fused QKV epilogue (N=6144): proj = bn>>11 -> Q/K scatter [b,h,s,hd],
//         V^T pack [b,h,hd,s]. MODE 1: fp32 [m][n] + bias.
template <int MODE>
__global__ __launch_bounds__(512, 2)
void k_gemm256(const short* __restrict__ A, const short* __restrict__ Bt,
               void* __restrict__ C0, void* __restrict__ C1, void* __restrict__ C2,
               const float* __restrict__ bias, int M, int N, int K) {
  __shared__ __align__(16) short As[2][2][8192];   // [buf][half][128 rows x 64 k]
  __shared__ __align__(16) short Bs[2][2][8192];
  const int tid = threadIdx.x;
  const int lane = tid & 63;
  const int wave = tid >> 6;
  const int ln = lane & 15, lq = lane >> 4;
  const int wr = wave >> 2, wc = wave & 3;        // 2M x 4N wave grid
  const int bn = blockIdx.x << 8;
  const int bm = blockIdx.y << 8;
  const int NT = K >> 6;

  // --- staging sources: lane covers LDS bytes [wave*1024 + lane*16) (+8192 for
  // inst 1).  r0 = row-in-half for inst0 (inst1 = r0+64, same k0).  k0 is the
  // inverse-swizzled k so linear LDS dest ends up swizzle-correct.
  const int r0 = wave * 8 + (lane >> 3);
  const int k0 = ((lane & 7) ^ ((lane >> 3) & 7)) << 3;
  const short* Ag0 = A  + (size_t)(bm + r0) * K + k0;
  const short* Ag1 = A  + (size_t)(bm + 128 + r0) * K + k0;
  const short* Bg0 = Bt + (size_t)(bn + ((r0 >> 5) << 6) + (r0 & 31)) * K + k0;
  const short* Bg1 = Bt + (size_t)(bn + (((r0 >> 5) + 2) << 6) + (r0 & 31)) * K + k0;
  const int ldst = wave * 512;                    // wave's 1 KiB chunk (shorts)

  // --- ds_read byte offsets (swizzled): row-in-half * 128 + ((ks*64+lq*16)^swz)
  const int swz = (ln & 7) << 4;
  const int rdA = (wr * 64 + ln) * 128;           // + mi*2048
  const int rdB = (wc * 32 + ln) * 128;           // + ni*2048
  const int cc0 = (lq * 16) ^ swz;                // ks = 0
  const int cc1 = (64 + lq * 16) ^ swz;           // ks = 1

  f32x4 acc[8][4];
#pragma unroll
  for (int i = 0; i < 8; i++)
#pragma unroll
    for (int j = 0; j < 4; j++) acc[i][j] = (f32x4)0.0f;

  // --- prologue: tile0 {A0,B0,B1,A1}, vmcnt(4), tile1 {A0,B0,B1}, vmcnt(6)
  STG_A(0, 0, 0);
  STG_B(0, 0, 0);
  STG_B(0, 1, 0);
  STG_A(0, 1, 0);
  asm volatile("s_waitcnt vmcnt(4)" ::: "memory");
  STG_A(1, 0, 1);
  STG_B(1, 0, 1);
  STG_B(1, 1, 1);
  asm volatile("s_waitcnt vmcnt(6)" ::: "memory");
  GBAR();

  short8 af[8];
  short8 bf0[4], bf1[4];

#pragma unroll 1
  for (int T = 0; T < NT; T += 2) {
    TILE(T, 0);
    TILE(T + 1, 1);
  }

  // --- epilogue (C/D layout: col=lane&15, row=(lane>>4)*4+reg — m89/m91)
  if (MODE == 0) {
    const int proj = bn >> 11;        // 0=Q, 1=K, 2=V (block-uniform, 256|2048)
    const int cb = bn & 2047;
    if (proj < 2) {
      short* C = (short*)(proj == 0 ? C0 : C1);
#pragma unroll
      for (int mi = 0; mi < 8; mi++)
#pragma unroll
        for (int ni = 0; ni < 4; ni++) {
          const int col = cb + wc * 64 + ni * 16 + ln;
          const int h = col >> 7, d = col & 127;
#pragma unroll
          for (int r = 0; r < 4; r++) {
            const int row = bm + wr * 128 + mi * 16 + lq * 4 + r;
            const int bb = row >> 11, s = row & 2047;
            C[((size_t)((bb * H_ + h) * S_ + s)) * HD_ + d] = f2bf(acc[mi][ni][r]);
          }
        }
    } else {  // V^T [b,h,d,s], r-regs = 4 consecutive s -> b64 store
      short* C = (short*)C2;
#pragma unroll
      for (int mi = 0; mi < 8; mi++)
#pragma unroll
        for (int ni = 0; ni < 4; ni++) {
          const int col = cb + wc * 64 + ni * 16 + ln;
          const int h = col >> 7, d = col & 127;
          const int row0 = bm + wr * 128 + mi * 16 + lq * 4;
          const int bb = row0 >> 11, s = row0 & 2047;
          short4v pk;
#pragma unroll
          for (int r = 0; r < 4; r++) pk[r] = f2bf(acc[mi][ni][r]);
          *(short4v*)(C + ((size_t)((bb * H_ + h) * HD_ + d)) * S_ + s) = pk;
        }
    }
  } else {
    float* C = (float*)C0;
#pragma unroll
    for (int mi = 0; mi < 8; mi++)
#pragma unroll
      for (int ni = 0; ni < 4; ni++) {
        const int col = bn + wc * 64 + ni * 16 + ln;
        const float bv = bias[col];
#pragma unroll
        for (int r = 0; r < 4; r++) {
          const int row = bm + wr * 128 + mi * 16 + lq * 4 + r;
          C[(size_t)row * N + col] = acc[mi][ni][r] + bv;
        }
      }
  }
}

// ---------------------------------------------------------------- flash attention
// v2: 8 waves / 256 q-rows per block (m214 shape).  KV staging amortized over
// 2x the q-rows (KV L2 traffic 590 -> 295 MB), 4 async16/wave/tile (was 8),
// half the barrier events per q-row.  Same dbuf/barrier/swizzle semantics.
// Grid: 256 blocks = 1/CU; block bx handles chunks cpair and 7-cpair (36 tiles
// each, perfectly balanced).  bh remap puts the 4 chunk-blocks of one head on
// the same XCD (KV L2 sharing).
__global__ __launch_bounds__(512)
void k_flash(const short* __restrict__ Q, const short* __restrict__ K,
             const short* __restrict__ Vt, short* __restrict__ ctx) {
  __shared__ __align__(16) short Ks[2][64 * 128];
  __shared__ __align__(16) short Vs[2][128 * 64];
  __shared__ __align__(16) short Ps[8 * 32 * 64];

  const int tid = threadIdx.x, lane = tid & 63, w = tid >> 6;
  const int ln = lane & 15, lq = lane >> 4;
  const int bx = blockIdx.x;
  const int bh = ((bx & 7) << 3) | ((bx >> 3) & 7);   // same-bh blocks share XCD
  const int cpair = bx >> 6;                          // 0..3
  const int b = bh >> 4, h = bh & 15;
  const short* Qp = Q  + (size_t)bh * S_ * HD_;
  const short* Kp = K  + (size_t)bh * S_ * HD_;
  const short* Vp = Vt + (size_t)bh * HD_ * S_;

  const float sc = 0.08838834764831845f * 1.4426950408889634f;
  const int lx = ln & 7;

  int koff[2], voff[2];
#pragma unroll
  for (int it = 0; it < 2; it++) {
    const int kr = w * 8 + it * 4 + (lane >> 4);
    koff[it] = kr * HD_ + (((lane & 15) ^ (kr & 7)) * 8);
    const int vr = w * 16 + it * 8 + (lane >> 3);
    voff[it] = vr * S_ + (((lane & 7) ^ (vr & 7)) * 8);
  }

#pragma unroll 1
  for (int pass = 0; pass < 2; pass++) {
    const int chunk = pass ? (7 - cpair) : cpair;    // 256-row q-chunk
    const int q0 = chunk << 8;
    const int qw = q0 + w * 32;
    const int nkt = chunk * 4 + 4;

    short8 qf[2][4];
#pragma unroll
    for (int nt = 0; nt < 2; nt++)
#pragma unroll
      for (int c = 0; c < 4; c++)
        qf[nt][c] = *(const short8*)(Qp + (size_t)(qw + nt * 16 + ln) * HD_ + c * 32 + lq * 8);

    f32x4 acc[8][2];
#pragma unroll
    for (int t = 0; t < 8; t++) { acc[t][0] = (f32x4)0.0f; acc[t][1] = (f32x4)0.0f; }
    float l_i[2] = {0.0f, 0.0f};

    __syncthreads();
#pragma unroll
    for (int it = 0; it < 2; it++) {
      async16(Kp + koff[it], &Ks[0][(w * 8 + it * 4) * 128]);
      async16(Vp + voff[it], &Vs[0][(w * 16 + it * 8) * 64]);
    }

#pragma unroll 1
    for (int kt = 0; kt < nkt; kt++) {
      const int k0 = kt << 6;
      const int cur = kt & 1;
      __syncthreads();
      if (kt + 1 < nkt) {
        const int nk0 = (kt + 1) << 6;
        const int nb = cur ^ 1;
#pragma unroll
        for (int it = 0; it < 2; it++) {
          async16(Kp + (size_t)nk0 * HD_ + koff[it], &Ks[nb][(w * 8 + it * 4) * 128]);
          async16(Vp + nk0 + voff[it],               &Vs[nb][(w * 16 + it * 8) * 64]);
        }
      }

      if (k0 <= qw + 31) {
        const short* KsC = Ks[cur];
        const short* VsC = Vs[cur];
        short* Pw = Ps + w * 32 * 64;
        const bool dg = (k0 + 63 > qw);

#pragma unroll
        for (int mt = 0; mt < 4; mt++) {
          f32x4 s0 = (f32x4)0.0f, s1 = (f32x4)0.0f;
#pragma unroll
          for (int c = 0; c < 4; c++) {
            short8 kf = *(const short8*)(KsC + (mt * 16 + ln) * 128 + (((4 * c + lq) ^ lx) * 8));
            s0 = __builtin_amdgcn_mfma_f32_16x16x32_bf16(kf, qf[0][c], s0, 0, 0, 0);
            s1 = __builtin_amdgcn_mfma_f32_16x16x32_bf16(kf, qf[1][c], s1, 0, 0, 0);
          }
          if (dg) {
#pragma unroll
            for (int r = 0; r < 4; r++) {
              const int kv = k0 + mt * 16 + lq * 4 + r;
              if (kv > qw + ln)      s0[r] = -INFINITY; else s0[r] *= sc;
              if (kv > qw + 16 + ln) s1[r] = -INFINITY; else s1[r] *= sc;
            }
          } else {
#pragma unroll
            for (int r = 0; r < 4; r++) { s0[r] *= sc; s1[r] *= sc; }
          }
#pragma unroll
          for (int r = 0; r < 4; r++) {
            s0[r] = exp2f(s0[r]); l_i[0] += s0[r];
            s1[r] = exp2f(s1[r]); l_i[1] += s1[r];
          }
          const int swc = (2 * mt + (lq >> 1)) ^ lx;
          const int po = swc * 8 + (lq & 1) * 4;
          *(uint2*)(Pw + ln * 64 + po)        = uint2{pk2(s0[0], s0[1]), pk2(s0[2], s0[3])};
          *(uint2*)(Pw + (16 + ln) * 64 + po) = uint2{pk2(s1[0], s1[1]), pk2(s1[2], s1[3])};
        }
        __asm__ volatile("s_waitcnt lgkmcnt(0)" ::: "memory");

#pragma unroll
        for (int c = 0; c < 2; c++) {
          const int swr = ((4 * c + lq) ^ lx) * 8;
          short8 pf0 = *(const short8*)(Pw + ln * 64 + swr);
          short8 pf1 = *(const short8*)(Pw + (16 + ln) * 64 + swr);
#pragma unroll
          for (int t = 0; t < 8; t++) {
            short8 vf = *(const short8*)(VsC + (t * 16 + ln) * 64 + swr);
            acc[t][0] = __builtin_amdgcn_mfma_f32_16x16x32_bf16(vf, pf0, acc[t][0], 0, 0, 0);
            acc[t][1] = __builtin_amdgcn_mfma_f32_16x16x32_bf16(vf, pf1, acc[t][1], 0, 0, 0);
          }
        }
      }
    }

#pragma unroll
    for (int o = 16; o < 64; o <<= 1) {
      l_i[0] += __shfl_xor(l_i[0], o, 64);
      l_i[1] += __shfl_xor(l_i[1], o, 64);
    }
    const float il[2] = {1.0f / l_i[0], 1.0f / l_i[1]};

#pragma unroll
    for (int t = 0; t < 8; t++)
#pragma unroll
      for (int nt = 0; nt < 2; nt++) {
        const int q = qw + nt * 16 + ln;
        const int d = t * 16 + lq * 4;
        uint2 o2 = {pk2(acc[t][nt][0] * il[nt], acc[t][nt][1] * il[nt]),
                    pk2(acc[t][nt][2] * il[nt], acc[t][nt][3] * il[nt])};
        *(uint2*)(ctx + ((size_t)(b * S_ + q)) * D_ + h * HD_ + d) = o2;
      }
  }
}

// ---------------------------------------------------------------- launch
extern "C" void kernel_launch(void* const* d_in, const int* in_sizes, int n_in,
                              void* d_out, int out_size, void* d_ws, size_t ws_size,
                              hipStream_t stream) {
  const float* x  = (const float*)d_in[0];
  const float* Wq = (const float*)d_in[1];
  const float* Wk = (const float*)d_in[2];
  const float* Wv = (const float*)d_in[3];
  const float* Wo = (const float*)d_in[4];
  const float* bo = (const float*)d_in[5];
  float* out = (float*)d_out;

  char* ws = (char*)d_ws;
  const size_t SZ_X = (size_t)M_ * D_ * sizeof(short);
  const size_t SZ_W = (size_t)D_ * D_ * sizeof(short);
  short* xb  = (short*)(ws);
  short* Wqt = (short*)(ws + SZ_X);                     // Wqt|Wkt|Wvt contiguous
  short* Wkt = (short*)(ws + SZ_X + SZ_W);              //  = fused B^T [6144][2048]
  short* Wvt = (short*)(ws + SZ_X + 2 * SZ_W);
  short* Wot = (short*)(ws + SZ_X + 3 * SZ_W);
  short* Qb  = (short*)(ws + SZ_X + 4 * SZ_W);
  short* Kb  = (short*)(ws + 2 * SZ_X + 4 * SZ_W);
  short* Vtb = (short*)(ws + 3 * SZ_X + 4 * SZ_W);      // V^T [b,h,d,s]
  short* ctx = (short*)(ws + 4 * SZ_X + 4 * SZ_W);      // total 192 MiB

  k_cvtx<<<M_ * D_ / 4 / 256, 256, 0, stream>>>(x, xb, M_ * D_ / 4);
  dim3 tg(D_ / 32, D_ / 32);
  k_wtrans<<<tg, 256, 0, stream>>>(Wq, Wqt);
  k_wtrans<<<tg, 256, 0, stream>>>(Wk, Wkt);
  k_wtrans<<<tg, 256, 0, stream>>>(Wv, Wvt);
  k_wtrans<<<tg, 256, 0, stream>>>(Wo, Wot);

  // fused QKV projection: N=6144, 768 blocks (24x32), 512 thr, 1 block/CU
  dim3 gq(3 * D_ / 256, M_ / 256);
  k_gemm256<0><<<gq, 512, 0, stream>>>(xb, Wqt, Qb, Kb, Vtb, nullptr, M_, 3 * D_, D_);

  // flash: 256 blocks (1/CU), 8 waves, 256 q-rows/block, 2 chunk-passes each
  k_flash<<<256, 512, 0, stream>>>(Qb, Kb, Vtb, ctx);

  // output projection: 256 blocks (8x32) = exactly 1 pass over 256 CUs
  dim3 go(D_ / 256, M_ / 256);
  k_gemm256<1><<<go, 512, 0, stream>>>(ctx, Wot, out, nullptr, nullptr, bo, M_, D_, D_);
}

// Round 4
// 550.143 us; speedup vs baseline: 1.1456x; 1.0059x over previous
//
#include <hip/hip_runtime.h>
#include <hip/hip_bf16.h>
#include <math.h>

// Problem constants (B=4, S=2048, D_IN=D_OUT=2048, H=16, HD=128)
#define H_   16
#define S_   2048
#define D_   2048
#define HD_  128
#define B_   4
#define M_   8192   // B*S

typedef __attribute__((ext_vector_type(8))) short short8;   // 8 bf16
typedef __attribute__((ext_vector_type(4))) short short4v;
typedef __attribute__((ext_vector_type(4))) float f32x4;

__device__ __forceinline__ short f2bf(float f) {
  unsigned u = __float_as_uint(f);
  u += 0x7fff + ((u >> 16) & 1);
  return (short)(u >> 16);
}

__device__ __forceinline__ unsigned pk2(float a, float b) {
  __hip_bfloat162 h = __float22bfloat162_rn(float2{a, b});
  union { __hip_bfloat162 h2; unsigned u; } c;
  c.h2 = h;
  return c.u;
}

__device__ __forceinline__ void async16(const void* g, void* l) {
  // 16B/lane, LDS dest = wave-uniform base + lane*16 (m97/m104 semantics)
  __builtin_amdgcn_global_load_lds(
      (const __attribute__((address_space(1))) void*)g,
      (__attribute__((address_space(3))) void*)l, 16, 0, 0);
}

// ---------------------------------------------------------------- cast x -> bf16
__global__ void k_cvtx(const float* __restrict__ x, short* __restrict__ o, int n4) {
  const int i = blockIdx.x * 256 + threadIdx.x;
  if (i >= n4) return;
  const float4 f = ((const float4*)x)[i];
  short4v s;
  s.x = f2bf(f.x); s.y = f2bf(f.y); s.z = f2bf(f.z); s.w = f2bf(f.w);
  ((short4v*)o)[i] = s;
}

// --------------------- W[K][N] fp32 -> Wt[N][K] bf16 (tiled); z selects weight
__global__ void k_wtrans4(const float* __restrict__ W0, const float* __restrict__ W1,
                          const float* __restrict__ W2, const float* __restrict__ W3,
                          short* __restrict__ T0, short* __restrict__ T1,
                          short* __restrict__ T2, short* __restrict__ T3) {
  __shared__ float t[32][33];
  const int z = blockIdx.z;
  const float* W = z == 0 ? W0 : z == 1 ? W1 : z == 2 ? W2 : W3;
  short* Wt      = z == 0 ? T0 : z == 1 ? T1 : z == 2 ? T2 : T3;
  const int n0 = blockIdx.x << 5, k0 = blockIdx.y << 5;
  const int tc = threadIdx.x & 31, tr = threadIdx.x >> 5;
#pragma unroll
  for (int i = 0; i < 32; i += 8)
    t[tr + i][tc] = W[(size_t)(k0 + tr + i) * D_ + n0 + tc];
  __syncthreads();
#pragma unroll
  for (int i = 0; i < 32; i += 8)
    Wt[(size_t)(n0 + tr + i) * D_ + k0 + tc] = f2bf(t[tc][tr + i]);
}

// =============================================================================
// 256x256 8-phase bf16 GEMM — R1 schedule (verified 222-233 us QKV, conflicts 0)
// + R4: chunked-bijective XCD swizzle (T1).  HW wgid w -> XCD w%8; logical id
// (w&7)*(nwg/8)+w/8 makes each XCD's resident blocks a CONTIGUOUS logical run:
// same A-panel shared 24x from own L2, per-XCD K-slice working set ~830 KB
// (<< 4 MB L2).  Theory: staging supply (measured 6.6 TB/s vs m201's 12-13)
// is the binding constraint; swizzle moves panel re-reads from L3 to L2.
// =============================================================================

#define GBAR() asm volatile("s_barrier" ::: "memory")
#define WLG0()                                          \
  do {                                                  \
    asm volatile("s_waitcnt lgkmcnt(0)" ::: "memory");  \
    __builtin_amdgcn_sched_barrier(0);                  \
  } while (0)

#define STG_A(b, mh, t)                                           \
  do {                                                            \
    const size_t o_ = (size_t)(t) * 64 + (size_t)(mh) * 64 * K;   \
    async16(Ag0 + o_, &As[b][mh][ldst]);                          \
    async16(Ag1 + o_, &As[b][mh][4096 + ldst]);                   \
  } while (0)

#define STG_B(b, nh, t)                                           \
  do {                                                            \
    const size_t o_ = (size_t)(t) * 64 + (size_t)(nh) * 32 * K;   \
    async16(Bg0 + o_, &Bs[b][nh][ldst]);                          \
    async16(Bg1 + o_, &Bs[b][nh][4096 + ldst]);                   \
  } while (0)

#define LDS_A(b, mh)                                                     \
  do {                                                                   \
    const char* a_ = (const char*)&As[b][mh][0];                         \
    _Pragma("unroll") for (int mi_ = 0; mi_ < 4; ++mi_) {                \
      af[mi_ * 2]     = *(const short8*)(a_ + rdA + mi_ * 2048 + cc0);   \
      af[mi_ * 2 + 1] = *(const short8*)(a_ + rdA + mi_ * 2048 + cc1);   \
    }                                                                    \
  } while (0)

#define LDS_B(b, nh, BF)                                                 \
  do {                                                                   \
    const char* b_ = (const char*)&Bs[b][nh][0];                         \
    _Pragma("unroll") for (int ni_ = 0; ni_ < 2; ++ni_) {                \
      BF[ni_ * 2]     = *(const short8*)(b_ + rdB + ni_ * 2048 + cc0);   \
      BF[ni_ * 2 + 1] = *(const short8*)(b_ + rdB + ni_ * 2048 + cc1);   \
    }                                                                    \
  } while (0)

#define QUAD(mh, nh, BF)                                                   \
  do {                                                                     \
    __builtin_amdgcn_s_setprio(1);                                         \
    _Pragma("unroll") for (int mi_ = 0; mi_ < 4; ++mi_)                    \
    _Pragma("unroll") for (int ni_ = 0; ni_ < 2; ++ni_) {                  \
      acc[(mh) * 4 + mi_][(nh) * 2 + ni_] =                                \
          __builtin_amdgcn_mfma_f32_16x16x32_bf16(                         \
              af[mi_ * 2], BF[ni_ * 2],                                    \
              acc[(mh) * 4 + mi_][(nh) * 2 + ni_], 0, 0, 0);               \
      acc[(mh) * 4 + mi_][(nh) * 2 + ni_] =                                \
          __builtin_amdgcn_mfma_f32_16x16x32_bf16(                         \
              af[mi_ * 2 + 1], BF[ni_ * 2 + 1],                            \
              acc[(mh) * 4 + mi_][(nh) * 2 + ni_], 0, 0, 0);               \
    }                                                                      \
    __builtin_amdgcn_s_setprio(0);                                         \
  } while (0)

#define TILE(T, b)                                                  \
  do {                                                              \
    /* ---- phase q=1: quadrant (0,0) ---- */                       \
    LDS_A(b, 0);                                                    \
    LDS_B(b, 0, bf0);                                               \
    if ((T) + 1 < NT) STG_A((b) ^ 1, 1, (T) + 1);                   \
    asm volatile("s_waitcnt lgkmcnt(8)" ::: "memory");              \
    GBAR();                                                         \
    WLG0();                                                         \
    QUAD(0, 0, bf0);                                                \
    GBAR();                                                         \
    /* ---- phase q=2: quadrant (0,1) ---- */                       \
    LDS_B(b, 1, bf1);                                               \
    if ((T) + 2 < NT) STG_A(b, 0, (T) + 2);                         \
    GBAR();                                                         \
    WLG0();                                                         \
    QUAD(0, 1, bf1);                                                \
    GBAR();                                                         \
    /* ---- phase q=3: quadrant (1,0) ---- */                       \
    LDS_A(b, 1);                                                    \
    if ((T) + 2 < NT) STG_B(b, 0, (T) + 2);                         \
    GBAR();                                                         \
    WLG0();                                                         \
    QUAD(1, 0, bf0);                                                \
    GBAR();                                                         \
    /* ---- phase q=4: quadrant (1,1) ---- */                       \
    if ((T) + 2 < NT) STG_B(b, 1, (T) + 2);                         \
    if ((T) + 2 < NT)                                               \
      asm volatile("s_waitcnt vmcnt(6)" ::: "memory");              \
    else if ((T) + 1 < NT)                                          \
      asm volatile("s_waitcnt vmcnt(0)" ::: "memory");              \
    GBAR();                                                         \
    QUAD(1, 1, bf1);                                                \
    GBAR();                                                         \
  } while (0)

// MODE 0: fused QKV epilogue (N=6144): proj = bn>>11 -> Q/K scatter [b,h,s,hd],
//         V^T pack [b,h,hd,s]. MODE 1: fp32 [m][n] + bias.
template <int MODE>
__global__ __launch_bounds__(512, 2)
void k_gemm256(const short* __restrict__ A, const short* __restrict__ Bt,
               void* __restrict__ C0, void* __restrict__ C1, void* __restrict__ C2,
               const float* __restrict__ bias, int M, int N, int K) {
  __shared__ __align__(16) short As[2][2][8192];   // [buf][half][128 rows x 64 k]
  __shared__ __align__(16) short Bs[2][2][8192];
  const int tid = threadIdx.x;
  const int lane = tid & 63;
  const int wave = tid >> 6;
  const int ln = lane & 15, lq = lane >> 4;
  const int wr = wave >> 2, wc = wave & 3;        // 2M x 4N wave grid

  // --- T1 chunked XCD swizzle: hw id w (x-fastest dispatch, XCD = w%8) ->
  // logical lg = (w&7)*cpx + w>>3; same-XCD blocks = contiguous logical run.
  const int gx = (MODE == 0) ? 24 : 8;            // gridDim.x (compile-time)
  const int nwg = (MODE == 0) ? 768 : 256;
  const int w = blockIdx.y * gx + blockIdx.x;
  const int lg = (w & 7) * (nwg >> 3) + (w >> 3);
  const int bn = (lg % gx) << 8;
  const int bm = (lg / gx) << 8;
  const int NT = K >> 6;

  // --- staging sources: lane covers LDS bytes [wave*1024 + lane*16) (+8192 for
  // inst 1).  r0 = row-in-half for inst0 (inst1 = r0+64, same k0).  k0 is the
  // inverse-swizzled k so linear LDS dest ends up swizzle-correct.
  const int r0 = wave * 8 + (lane >> 3);
  const int k0 = ((lane & 7) ^ ((lane >> 3) & 7)) << 3;
  const short* Ag0 = A  + (size_t)(bm + r0) * K + k0;
  const short* Ag1 = A  + (size_t)(bm + 128 + r0) * K + k0;
  const short* Bg0 = Bt + (size_t)(bn + ((r0 >> 5) << 6) + (r0 & 31)) * K + k0;
  const short* Bg1 = Bt + (size_t)(bn + (((r0 >> 5) + 2) << 6) + (r0 & 31)) * K + k0;
  const int ldst = wave * 512;                    // wave's 1 KiB chunk (shorts)

  // --- ds_read byte offsets (swizzled): row-in-half * 128 + ((ks*64+lq*16)^swz)
  const int swz = (ln & 7) << 4;
  const int rdA = (wr * 64 + ln) * 128;           // + mi*2048
  const int rdB = (wc * 32 + ln) * 128;           // + ni*2048
  const int cc0 = (lq * 16) ^ swz;                // ks = 0
  const int cc1 = (64 + lq * 16) ^ swz;           // ks = 1

  f32x4 acc[8][4];
#pragma unroll
  for (int i = 0; i < 8; i++)
#pragma unroll
    for (int j = 0; j < 4; j++) acc[i][j] = (f32x4)0.0f;

  // --- prologue: tile0 {A0,B0,B1,A1}, vmcnt(4), tile1 {A0,B0,B1}, vmcnt(6)
  STG_A(0, 0, 0);
  STG_B(0, 0, 0);
  STG_B(0, 1, 0);
  STG_A(0, 1, 0);
  asm volatile("s_waitcnt vmcnt(4)" ::: "memory");
  STG_A(1, 0, 1);
  STG_B(1, 0, 1);
  STG_B(1, 1, 1);
  asm volatile("s_waitcnt vmcnt(6)" ::: "memory");
  GBAR();

  short8 af[8];
  short8 bf0[4], bf1[4];

#pragma unroll 1
  for (int T = 0; T < NT; T += 2) {
    TILE(T, 0);
    TILE(T + 1, 1);
  }

  // --- epilogue (C/D layout: col=lane&15, row=(lane>>4)*4+reg — m89/m91)
  if (MODE == 0) {
    const int proj = bn >> 11;        // 0=Q, 1=K, 2=V (block-uniform, 256|2048)
    const int cb = bn & 2047;
    if (proj < 2) {
      short* C = (short*)(proj == 0 ? C0 : C1);
#pragma unroll
      for (int mi = 0; mi < 8; mi++)
#pragma unroll
        for (int ni = 0; ni < 4; ni++) {
          const int col = cb + wc * 64 + ni * 16 + ln;
          const int h = col >> 7, d = col & 127;
#pragma unroll
          for (int r = 0; r < 4; r++) {
            const int row = bm + wr * 128 + mi * 16 + lq * 4 + r;
            const int bb = row >> 11, s = row & 2047;
            C[((size_t)((bb * H_ + h) * S_ + s)) * HD_ + d] = f2bf(acc[mi][ni][r]);
          }
        }
    } else {  // V^T [b,h,d,s], r-regs = 4 consecutive s -> b64 store
      short* C = (short*)C2;
#pragma unroll
      for (int mi = 0; mi < 8; mi++)
#pragma unroll
        for (int ni = 0; ni < 4; ni++) {
          const int col = cb + wc * 64 + ni * 16 + ln;
          const int h = col >> 7, d = col & 127;
          const int row0 = bm + wr * 128 + mi * 16 + lq * 4;
          const int bb = row0 >> 11, s = row0 & 2047;
          short4v pk;
#pragma unroll
          for (int r = 0; r < 4; r++) pk[r] = f2bf(acc[mi][ni][r]);
          *(short4v*)(C + ((size_t)((bb * H_ + h) * HD_ + d)) * S_ + s) = pk;
        }
    }
  } else {
    float* C = (float*)C0;
#pragma unroll
    for (int mi = 0; mi < 8; mi++)
#pragma unroll
      for (int ni = 0; ni < 4; ni++) {
        const int col = bn + wc * 64 + ni * 16 + ln;
        const float bv = bias[col];
#pragma unroll
        for (int r = 0; r < 4; r++) {
          const int row = bm + wr * 128 + mi * 16 + lq * 4 + r;
          C[(size_t)row * N + col] = acc[mi][ni][r] + bv;
        }
      }
  }
}

// ---------------------------------------------------------------- flash attention
// 8 waves / 256 q-rows per block (R3: WIN, ~191 -> ~115 us).  KV staged via
// async16 dbuf; __syncthreads drains the prefetch issued one full compute
// phase earlier.  R4: + s_setprio around MFMA clusters (T5 hint).
__global__ __launch_bounds__(512)
void k_flash(const short* __restrict__ Q, const short* __restrict__ K,
             const short* __restrict__ Vt, short* __restrict__ ctx) {
  __shared__ __align__(16) short Ks[2][64 * 128];
  __shared__ __align__(16) short Vs[2][128 * 64];
  __shared__ __align__(16) short Ps[8 * 32 * 64];

  const int tid = threadIdx.x, lane = tid & 63, w = tid >> 6;
  const int ln = lane & 15, lq = lane >> 4;
  const int bx = blockIdx.x;
  const int bh = ((bx & 7) << 3) | ((bx >> 3) & 7);   // same-bh blocks share XCD
  const int cpair = bx >> 6;                          // 0..3
  const int b = bh >> 4, h = bh & 15;
  const short* Qp = Q  + (size_t)bh * S_ * HD_;
  const short* Kp = K  + (size_t)bh * S_ * HD_;
  const short* Vp = Vt + (size_t)bh * HD_ * S_;

  const float sc = 0.08838834764831845f * 1.4426950408889634f;
  const int lx = ln & 7;

  int koff[2], voff[2];
#pragma unroll
  for (int it = 0; it < 2; it++) {
    const int kr = w * 8 + it * 4 + (lane >> 4);
    koff[it] = kr * HD_ + (((lane & 15) ^ (kr & 7)) * 8);
    const int vr = w * 16 + it * 8 + (lane >> 3);
    voff[it] = vr * S_ + (((lane & 7) ^ (vr & 7)) * 8);
  }

#pragma unroll 1
  for (int pass = 0; pass < 2; pass++) {
    const int chunk = pass ? (7 - cpair) : cpair;    // 256-row q-chunk
    const int q0 = chunk << 8;
    const int qw = q0 + w * 32;
    const int nkt = chunk * 4 + 4;

    short8 qf[2][4];
#pragma unroll
    for (int nt = 0; nt < 2; nt++)
#pragma unroll
      for (int c = 0; c < 4; c++)
        qf[nt][c] = *(const short8*)(Qp + (size_t)(qw + nt * 16 + ln) * HD_ + c * 32 + lq * 8);

    f32x4 acc[8][2];
#pragma unroll
    for (int t = 0; t < 8; t++) { acc[t][0] = (f32x4)0.0f; acc[t][1] = (f32x4)0.0f; }
    float l_i[2] = {0.0f, 0.0f};

    __syncthreads();
#pragma unroll
    for (int it = 0; it < 2; it++) {
      async16(Kp + koff[it], &Ks[0][(w * 8 + it * 4) * 128]);
      async16(Vp + voff[it], &Vs[0][(w * 16 + it * 8) * 64]);
    }

#pragma unroll 1
    for (int kt = 0; kt < nkt; kt++) {
      const int k0 = kt << 6;
      const int cur = kt & 1;
      __syncthreads();
      if (kt + 1 < nkt) {
        const int nk0 = (kt + 1) << 6;
        const int nb = cur ^ 1;
#pragma unroll
        for (int it = 0; it < 2; it++) {
          async16(Kp + (size_t)nk0 * HD_ + koff[it], &Ks[nb][(w * 8 + it * 4) * 128]);
          async16(Vp + nk0 + voff[it],               &Vs[nb][(w * 16 + it * 8) * 64]);
        }
      }

      if (k0 <= qw + 31) {
        const short* KsC = Ks[cur];
        const short* VsC = Vs[cur];
        short* Pw = Ps + w * 32 * 64;
        const bool dg = (k0 + 63 > qw);

#pragma unroll
        for (int mt = 0; mt < 4; mt++) {
          f32x4 s0 = (f32x4)0.0f, s1 = (f32x4)0.0f;
          __builtin_amdgcn_s_setprio(1);
#pragma unroll
          for (int c = 0; c < 4; c++) {
            short8 kf = *(const short8*)(KsC + (mt * 16 + ln) * 128 + (((4 * c + lq) ^ lx) * 8));
            s0 = __builtin_amdgcn_mfma_f32_16x16x32_bf16(kf, qf[0][c], s0, 0, 0, 0);
            s1 = __builtin_amdgcn_mfma_f32_16x16x32_bf16(kf, qf[1][c], s1, 0, 0, 0);
          }
          __builtin_amdgcn_s_setprio(0);
          if (dg) {
#pragma unroll
            for (int r = 0; r < 4; r++) {
              const int kv = k0 + mt * 16 + lq * 4 + r;
              if (kv > qw + ln)      s0[r] = -INFINITY; else s0[r] *= sc;
              if (kv > qw + 16 + ln) s1[r] = -INFINITY; else s1[r] *= sc;
            }
          } else {
#pragma unroll
            for (int r = 0; r < 4; r++) { s0[r] *= sc; s1[r] *= sc; }
          }
#pragma unroll
          for (int r = 0; r < 4; r++) {
            s0[r] = exp2f(s0[r]); l_i[0] += s0[r];
            s1[r] = exp2f(s1[r]); l_i[1] += s1[r];
          }
          const int swc = (2 * mt + (lq >> 1)) ^ lx;
          const int po = swc * 8 + (lq & 1) * 4;
          *(uint2*)(Pw + ln * 64 + po)        = uint2{pk2(s0[0], s0[1]), pk2(s0[2], s0[3])};
          *(uint2*)(Pw + (16 + ln) * 64 + po) = uint2{pk2(s1[0], s1[1]), pk2(s1[2], s1[3])};
        }
        __asm__ volatile("s_waitcnt lgkmcnt(0)" ::: "memory");

#pragma unroll
        for (int c = 0; c < 2; c++) {
          const int swr = ((4 * c + lq) ^ lx) * 8;
          short8 pf0 = *(const short8*)(Pw + ln * 64 + swr);
          short8 pf1 = *(const short8*)(Pw + (16 + ln) * 64 + swr);
          __builtin_amdgcn_s_setprio(1);
#pragma unroll
          for (int t = 0; t < 8; t++) {
            short8 vf = *(const short8*)(VsC + (t * 16 + ln) * 64 + swr);
            acc[t][0] = __builtin_amdgcn_mfma_f32_16x16x32_bf16(vf, pf0, acc[t][0], 0, 0, 0);
            acc[t][1] = __builtin_amdgcn_mfma_f32_16x16x32_bf16(vf, pf1, acc[t][1], 0, 0, 0);
          }
          __builtin_amdgcn_s_setprio(0);
        }
      }
    }

#pragma unroll
    for (int o = 16; o < 64; o <<= 1) {
      l_i[0] += __shfl_xor(l_i[0], o, 64);
      l_i[1] += __shfl_xor(l_i[1], o, 64);
    }
    const float il[2] = {1.0f / l_i[0], 1.0f / l_i[1]};

#pragma unroll
    for (int t = 0; t < 8; t++)
#pragma unroll
      for (int nt = 0; nt < 2; nt++) {
        const int q = qw + nt * 16 + ln;
        const int d = t * 16 + lq * 4;
        uint2 o2 = {pk2(acc[t][nt][0] * il[nt], acc[t][nt][1] * il[nt]),
                    pk2(acc[t][nt][2] * il[nt], acc[t][nt][3] * il[nt])};
        *(uint2*)(ctx + ((size_t)(b * S_ + q)) * D_ + h * HD_ + d) = o2;
      }
  }
}

// ---------------------------------------------------------------- launch
extern "C" void kernel_launch(void* const* d_in, const int* in_sizes, int n_in,
                              void* d_out, int out_size, void* d_ws, size_t ws_size,
                              hipStream_t stream) {
  const float* x  = (const float*)d_in[0];
  const float* Wq = (const float*)d_in[1];
  const float* Wk = (const float*)d_in[2];
  const float* Wv = (const float*)d_in[3];
  const float* Wo = (const float*)d_in[4];
  const float* bo = (const float*)d_in[5];
  float* out = (float*)d_out;

  char* ws = (char*)d_ws;
  const size_t SZ_X = (size_t)M_ * D_ * sizeof(short);
  const size_t SZ_W = (size_t)D_ * D_ * sizeof(short);
  short* xb  = (short*)(ws);
  short* Wqt = (short*)(ws + SZ_X);                     // Wqt|Wkt|Wvt contiguous
  short* Wkt = (short*)(ws + SZ_X + SZ_W);              //  = fused B^T [6144][2048]
  short* Wvt = (short*)(ws + SZ_X + 2 * SZ_W);
  short* Wot = (short*)(ws + SZ_X + 3 * SZ_W);
  short* Qb  = (short*)(ws + SZ_X + 4 * SZ_W);
  short* Kb  = (short*)(ws + 2 * SZ_X + 4 * SZ_W);
  short* Vtb = (short*)(ws + 3 * SZ_X + 4 * SZ_W);      // V^T [b,h,d,s]
  short* ctx = (short*)(ws + 4 * SZ_X + 4 * SZ_W);      // total 192 MiB

  k_cvtx<<<M_ * D_ / 4 / 256, 256, 0, stream>>>(x, xb, M_ * D_ / 4);
  dim3 tg(D_ / 32, D_ / 32, 4);
  k_wtrans4<<<tg, 256, 0, stream>>>(Wq, Wk, Wv, Wo, Wqt, Wkt, Wvt, Wot);

  // fused QKV projection: N=6144, 768 blocks (24x32), 512 thr, 1 block/CU
  dim3 gq(3 * D_ / 256, M_ / 256);
  k_gemm256<0><<<gq, 512, 0, stream>>>(xb, Wqt, Qb, Kb, Vtb, nullptr, M_, 3 * D_, D_);

  // flash: 256 blocks (1/CU), 8 waves, 256 q-rows/block, 2 chunk-passes each
  k_flash<<<256, 512, 0, stream>>>(Qb, Kb, Vtb, ctx);

  // output projection: 256 blocks (8x32) = exactly 1 pass over 256 CUs
  dim3 go(D_ / 256, M_ / 256);
  k_gemm256<1><<<go, 512, 0, stream>>>(ctx, Wot, out, nullptr, nullptr, bo, M_, D_, D_);
}